// Round 1
// baseline (672.567 us; speedup 1.0000x reference)
//
#include <hip/hip_runtime.h>
#include <hip/hip_bf16.h>

// FSAS_26766236188756 — round 6: k3 occupancy (bf16 LDS staging, 36.8KB -> 4 blk/CU)
// + XCD-aware patch swizzle to kill partial-line write amplification.
// kx: x [b][c][hw] fp32 -> XT [b][hw][c] bf16
// k0: wpT fp32 transpose [128][64]
// k1: MFMA 1x1 conv 64->384, hid bf16 [384][HW] row-major
// k2: dw 3x3 -> qkv bf16 PATCH-MAJOR [384][1024 patches][64 px]
// k3: per-patch circ conv + LN + *v + proj -> out fp32

typedef unsigned short ushort;
typedef __attribute__((ext_vector_type(8))) short short8;
typedef __attribute__((ext_vector_type(4))) float floatx4;
typedef __attribute__((ext_vector_type(2))) unsigned int uint2v;
typedef __attribute__((ext_vector_type(4))) unsigned int uint4v;

#define CC 64
#define HID 384
#define HW 65536
#define QSU 68     // qb/kb row stride (ushorts, bf16): 136B -> +2 banks/row, b64-aligned
#define TS 68      // t row stride (floats)

#define WPT_OFF 0
#define XT_OFF  131072
#define XT_BYTES (4ull * HW * 64 * 2)
#define HID_OFF (XT_OFF + XT_BYTES)
#define HID_BYTES (384ull * HW * 2)
#define QKV_OFF (HID_OFF + HID_BYTES)

__device__ __forceinline__ float bu2f(ushort u) {
    union { float f; unsigned i; } v; v.i = ((unsigned)u) << 16; return v.f;
}
__device__ __forceinline__ ushort f2bu(float f) {
    __hip_bfloat16 h = __float2bfloat16(f);
    return *(ushort*)&h;
}
// packed dword of 2 bf16 -> 2 floats (1 VALU op per value)
__device__ __forceinline__ void unpk(unsigned d, float& lo, float& hi) {
    union { unsigned i; float f; } a, b;
    a.i = d << 16; b.i = d & 0xffff0000u;
    lo = a.f; hi = b.f;
}

__global__ __launch_bounds__(256) void kx_tr(
    const float* __restrict__ x, ushort* __restrict__ XT) {
    int b = blockIdx.y;
    int hw = blockIdx.x * 256 + threadIdx.x;
    const float* xb = x + ((size_t)b * CC) * HW;
    ushort* XTb = XT + ((size_t)b * HW + hw) * 64;
#pragma unroll 2
    for (int c0 = 0; c0 < 64; c0 += 8) {
        ushort v[8];
#pragma unroll
        for (int j = 0; j < 8; j++)
            v[j] = f2bu(xb[(size_t)(c0 + j) * HW + hw]);
        *(short8*)(XTb + c0) = *(short8*)v;
    }
}

// k0: wpT [c][o] = wp[o][c] fp32; WS mfma-swizzled w_hidden bf16
__global__ __launch_bounds__(256) void k0_prep(
    const float* __restrict__ wp, const float* __restrict__ wh,
    float* __restrict__ wpT, ushort* __restrict__ WS) {
    int t = threadIdx.x;
    for (int i = t; i < 8192; i += 256) {
        int c = i >> 6, o = i & 63;
        wpT[i] = wp[o * 128 + c];
    }
    for (int i = t; i < 24576; i += 256) {
        int j = i & 7;
        int lane = (i >> 3) & 63;
        int ks = (i >> 9) & 1;
        int mt = i >> 10;
        int o = mt * 16 + (lane & 15);
        int k = ks * 32 + ((lane >> 4) << 3) + j;
        WS[i] = f2bu(wh[o * 64 + k]);
    }
}

#define WS_OFF 32768

// k1: MFMA GEMM 64->384. Block 4 waves: 64 out x 256 pix.
__global__ __launch_bounds__(256) void k1_mfma(
    const ushort* __restrict__ XT, const ushort* __restrict__ WS,
    const float* __restrict__ bh, ushort* __restrict__ hid) {
    int tid = threadIdx.x;
    int lane = tid & 63, wave = tid >> 6;
    int lane15 = lane & 15, quad = lane >> 4;
    int pix0 = blockIdx.x * 256 + wave * 64;
    int o0 = blockIdx.y * 64;

    short8 a[4][2];
#pragma unroll
    for (int mt = 0; mt < 4; mt++) {
        int mtg = (o0 >> 4) + mt;
#pragma unroll
        for (int ks = 0; ks < 2; ks++)
            a[mt][ks] = *(const short8*)(WS + ((((mtg << 1) + ks) << 6) + lane) * 8);
    }
    floatx4 acc[4][4];
#pragma unroll
    for (int mt = 0; mt < 4; mt++)
#pragma unroll
        for (int nt = 0; nt < 4; nt++)
            acc[mt][nt] = (floatx4){0.f, 0.f, 0.f, 0.f};

#pragma unroll
    for (int nt = 0; nt < 4; nt++) {
        const ushort* bp0 = XT + ((size_t)(pix0 + nt * 16 + lane15) << 6) + quad * 8;
        short8 b0 = *(const short8*)(bp0);
        short8 b1 = *(const short8*)(bp0 + 32);
#pragma unroll
        for (int mt = 0; mt < 4; mt++) {
            acc[mt][nt] = __builtin_amdgcn_mfma_f32_16x16x32_bf16(a[mt][0], b0, acc[mt][nt], 0, 0, 0);
            acc[mt][nt] = __builtin_amdgcn_mfma_f32_16x16x32_bf16(a[mt][1], b1, acc[mt][nt], 0, 0, 0);
        }
    }
#pragma unroll
    for (int mt = 0; mt < 4; mt++) {
        int obase = o0 + mt * 16 + quad * 4;
        float b0 = bh[obase], b1 = bh[obase + 1], b2 = bh[obase + 2], b3 = bh[obase + 3];
#pragma unroll
        for (int nt = 0; nt < 4; nt++) {
            int pix = pix0 + nt * 16 + lane15;
            hid[(size_t)(obase + 0) * HW + pix] = f2bu(acc[mt][nt][0] + b0);
            hid[(size_t)(obase + 1) * HW + pix] = f2bu(acc[mt][nt][1] + b1);
            hid[(size_t)(obase + 2) * HW + pix] = f2bu(acc[mt][nt][2] + b2);
            hid[(size_t)(obase + 3) * HW + pix] = f2bu(acc[mt][nt][3] + b3);
        }
    }
}

// k2: dw 3x3 SAME + bias -> qkv PATCH-MAJOR [ch][patch][64].
// Block = 8 rows (one patch-row) x 1 ch. grid (32, 384).
__global__ __launch_bounds__(256) void k2_dw(
    const ushort* __restrict__ hid, const float* __restrict__ wdw,
    const float* __restrict__ bdw, ushort* __restrict__ qkv) {
    __shared__ float rows[10][258];
    __shared__ ushort stg[8 * 264];
    int tid = threadIdx.x;
    int ch = blockIdx.y;
    int pr = blockIdx.x;               // patch-row 0..31
    int r0 = pr * 8;
    const ushort* base = hid + (size_t)ch * HW;
    for (int rr = 0; rr < 10; rr++) {
        int r = r0 - 1 + rr;
        float v = 0.f;
        if (r >= 0 && r < 256) v = bu2f(base[(r << 8) + tid]);
        rows[rr][1 + tid] = v;
        if (tid == 0) { rows[rr][0] = 0.f; rows[rr][257] = 0.f; }
    }
    __syncthreads();
    float w00 = wdw[ch * 9 + 0], w01 = wdw[ch * 9 + 1], w02 = wdw[ch * 9 + 2];
    float w10 = wdw[ch * 9 + 3], w11 = wdw[ch * 9 + 4], w12 = wdw[ch * 9 + 5];
    float w20 = wdw[ch * 9 + 6], w21 = wdw[ch * 9 + 7], w22 = wdw[ch * 9 + 8];
    float bias = bdw[ch];
#pragma unroll
    for (int rr = 0; rr < 8; rr++) {
        float acc = bias
            + w00 * rows[rr][tid] + w01 * rows[rr][tid + 1] + w02 * rows[rr][tid + 2]
            + w10 * rows[rr + 1][tid] + w11 * rows[rr + 1][tid + 1] + w12 * rows[rr + 1][tid + 2]
            + w20 * rows[rr + 2][tid] + w21 * rows[rr + 2][tid + 1] + w22 * rows[rr + 2][tid + 2];
        stg[rr * 264 + tid] = f2bu(acc);
    }
    __syncthreads();
    // patch-major writeout: thread t -> 8 contiguous ushorts (fully coalesced 4KB)
    short8 v = *(const short8*)(stg + (tid & 7) * 264 + (tid >> 3) * 8);
    *(short8*)(qkv + (size_t)ch * HW + (size_t)pr * 2048 + tid * 8) = v;
}

// k3: per-patch circ conv + LN + *v + proj. qkv patch-major.
// Round-6: bf16 q/k staging (LDS 36864B -> 4 blocks/CU), wp read from global (L1),
// XCD swizzle so each XCD owns 128 contiguous patches (full output lines per L2).
__global__ __launch_bounds__(256, 4) void k3_patch(
    const ushort* __restrict__ qkv, const float* __restrict__ wpTg,
    const float* __restrict__ bp, const float* __restrict__ lnw,
    const float* __restrict__ lnb, float* __restrict__ out, int b) {
    __shared__ float SH[9216];          // 36864 B
    ushort* qb_u = (ushort*)SH;         // bf16 [128][QSU]
    ushort* kb_u = (ushort*)SH + 8704;  // bf16 [128][QSU]
    float* tb = SH;                     // fp32 [128][TS] overlay (after B)
    float* red = SH + 8704;             // 512 floats

    int tid = threadIdx.x;
    int bid = blockIdx.x;
    // XCD-aware swizzle (grid=1024, 8 XCDs): xcd = bid%8 gets patches [xcd*128, +128)
    int p = ((bid & 7) << 7) | (bid >> 3);
    int prow = p >> 5, pcol = p & 31;

    // Phase A: coalesced patch-major loads -> bf16 LDS (stride QSU=68 ushorts)
#pragma unroll
    for (int m = 0; m < 4; m++) {
        int f = m * 256 + tid;
        int c = f >> 3;
        int i8 = (f & 7) * 8;
        uint4v qv = *(const uint4v*)(qkv + (size_t)c * HW + (size_t)p * 64 + i8);
        uint4v kv = *(const uint4v*)(qkv + (size_t)(128 + c) * HW + (size_t)p * 64 + i8);
        uint2v* qd = (uint2v*)(qb_u + c * QSU + i8);
        uint2v* kd = (uint2v*)(kb_u + c * QSU + i8);
        qd[0] = (uint2v){qv.x, qv.y};
        qd[1] = (uint2v){qv.z, qv.w};
        kd[0] = (uint2v){kv.x, kv.y};
        kd[1] = (uint2v){kv.z, kv.w};
    }
    __syncthreads();

    // Phase B: 2D circular conv. thread = (channel c, col-half h).
    int c = tid >> 1, h = tid & 1;
    float qr[64];
    {
        const ushort* qrow = qb_u + c * QSU;
#pragma unroll
        for (int j = 0; j < 16; j++) {
            uint2v d = *(const uint2v*)(qrow + 4 * j);
            unpk(d.x, qr[4 * j], qr[4 * j + 1]);
            unpk(d.y, qr[4 * j + 2], qr[4 * j + 3]);
        }
    }
    float acc[8][4];
#pragma unroll
    for (int r = 0; r < 8; r++)
#pragma unroll
        for (int sc = 0; sc < 4; sc++) acc[r][sc] = 0.f;
    {
        const ushort* krow = kb_u + c * QSU;
#pragma unroll 2
        for (int m = 0; m < 8; m++) {
            float kr[8];   // kr[v] = k[c][m][(v+4h)&7]
#pragma unroll
            for (int u2 = 0; u2 < 4; u2++) {
                int colo = (u2 * 2 + 4 * h) & 7;
                unsigned d = *(const unsigned*)(krow + m * 8 + colo);
                unpk(d, kr[u2 * 2], kr[u2 * 2 + 1]);
            }
#pragma unroll
            for (int r = 0; r < 8; r++) {
                int i = (r - m) & 7;
#pragma unroll
                for (int sc = 0; sc < 4; sc++)
#pragma unroll
                    for (int j = 0; j < 8; j++)
                        acc[r][sc] += qr[i * 8 + j] * kr[(sc - j) & 7];
            }
        }
    }
    __syncthreads();

    // Phase C: t -> LDS fp32 (stride TS=68), overlays q/k staging
#pragma unroll
    for (int r = 0; r < 8; r++) {
        float4 v = {acc[r][0], acc[r][1], acc[r][2], acc[r][3]};
        *(float4*)(tb + c * TS + r * 8 + h * 4) = v;
    }
    __syncthreads();

    // LN: per-pixel stats over 128 ch
    int pix = tid & 63, cg = tid >> 6;
    float sum = 0.f, sq = 0.f;
#pragma unroll
    for (int j = 0; j < 32; j++) {
        int cc = cg * 32 + j;
        float v = tb[cc * TS + pix];
        sum += v; sq += v * v;
    }
    red[cg * 64 + pix] = sum;
    red[256 + cg * 64 + pix] = sq;
    __syncthreads();
    float ts = red[pix] + red[64 + pix] + red[128 + pix] + red[192 + pix];
    float tq = red[256 + pix] + red[320 + pix] + red[384 + pix] + red[448 + pix];
    float mu = ts * (1.f / 128.f);
    float var = tq * (1.f / 128.f) - mu * mu;
    float rsig = rsqrtf(var + 1e-5f);

    // Phase D: t = ((t-mu)*rsig*lnw + lnb) * v   (in-place, per-pixel exclusive)
#pragma unroll 4
    for (int j = 0; j < 32; j++) {
        int cc = cg * 32 + j;
        float vv = bu2f(qkv[(size_t)(256 + cc) * HW + (size_t)p * 64 + pix]);
        float tv = tb[cc * TS + pix];
        tb[cc * TS + pix] = ((tv - mu) * rsig * lnw[cc] + lnb[cc]) * vv;
    }
    __syncthreads();

    // Phase E: proj 128->64, thread tile 4 out x 4 pix.
    // wpT read straight from global: 32KB shared by all blocks -> L1/L2 resident.
    int oi = tid & 15, pg = tid >> 4;
    int o0 = oi * 4, pix0 = pg * 4;
    float pe[4][4];
#pragma unroll
    for (int oo = 0; oo < 4; oo++) {
        float bb = bp[o0 + oo];
#pragma unroll
        for (int pp = 0; pp < 4; pp++) pe[oo][pp] = bb;
    }
#pragma unroll 4
    for (int cc = 0; cc < 128; cc++) {
        float4 wv = *(const float4*)(wpTg + cc * 64 + o0);
        float4 tv = *(const float4*)(tb + cc * TS + pix0);
        pe[0][0] += wv.x * tv.x; pe[0][1] += wv.x * tv.y; pe[0][2] += wv.x * tv.z; pe[0][3] += wv.x * tv.w;
        pe[1][0] += wv.y * tv.x; pe[1][1] += wv.y * tv.y; pe[1][2] += wv.y * tv.z; pe[1][3] += wv.y * tv.w;
        pe[2][0] += wv.z * tv.x; pe[2][1] += wv.z * tv.y; pe[2][2] += wv.z * tv.z; pe[2][3] += wv.z * tv.w;
        pe[3][0] += wv.w * tv.x; pe[3][1] += wv.w * tv.y; pe[3][2] += wv.w * tv.z; pe[3][3] += wv.w * tv.w;
    }
    int row = (prow << 3) + (pix0 >> 3);
    int col = (pcol << 3) + (pix0 & 7);
#pragma unroll
    for (int oo = 0; oo < 4; oo++) {
        float4 v = {pe[oo][0], pe[oo][1], pe[oo][2], pe[oo][3]};
        *(float4*)(out + (((size_t)(b * CC + o0 + oo)) << 16) + row * 256 + col) = v;
    }
}

extern "C" void kernel_launch(void* const* d_in, const int* in_sizes, int n_in,
                              void* d_out, int out_size, void* d_ws, size_t ws_size,
                              hipStream_t stream) {
    (void)in_sizes; (void)n_in; (void)out_size; (void)ws_size;
    const float* x   = (const float*)d_in[0];
    const float* wh  = (const float*)d_in[1];
    const float* bh  = (const float*)d_in[2];
    const float* wdw = (const float*)d_in[3];
    const float* bdw = (const float*)d_in[4];
    const float* wp  = (const float*)d_in[5];
    const float* bp  = (const float*)d_in[6];
    const float* lnw = (const float*)d_in[7];
    const float* lnb = (const float*)d_in[8];
    float* out = (float*)d_out;

    char* ws = (char*)d_ws;
    float* wpT = (float*)(ws + WPT_OFF);
    ushort* WS = (ushort*)(ws + WS_OFF);
    ushort* XT = (ushort*)(ws + XT_OFF);
    ushort* hid = (ushort*)(ws + HID_OFF);
    ushort* qkv = (ushort*)(ws + QKV_OFF);

    kx_tr<<<dim3(256, 4), dim3(256), 0, stream>>>(x, XT);
    k0_prep<<<dim3(1), dim3(256), 0, stream>>>(wp, wh, wpT, WS);

    for (int b = 0; b < 4; b++) {
        k1_mfma<<<dim3(256, 6), dim3(256), 0, stream>>>(
            XT + (size_t)b * HW * 64, WS, bh, hid);
        k2_dw<<<dim3(32, HID), dim3(256), 0, stream>>>(hid, wdw, bdw, qkv);
        k3_patch<<<dim3(1024), dim3(256), 0, stream>>>(qkv, wpT, bp, lnw, lnb, out, b);
    }
}

// Round 2
// 633.193 us; speedup vs baseline: 1.0622x; 1.0622x over previous
//
#include <hip/hip_runtime.h>
#include <hip/hip_bf16.h>

// FSAS_26766236188756 — round 7: k3 = bf16 q/k staging (kept from r6) + wp back in
// LDS but CHUNKED in 2x16KB halves -> 53,248B LDS -> 3 blocks/CU, wp reads at LDS
// latency. Chunk1 copied during phase A (hidden), chunk2 via registers at phase C.
// kx: x [b][c][hw] fp32 -> XT [b][hw][c] bf16
// k0: wpT fp32 transpose [128][64]
// k1: MFMA 1x1 conv 64->384, hid bf16 [384][HW] row-major
// k2: dw 3x3 -> qkv bf16 PATCH-MAJOR [384][1024 patches][64 px]
// k3: per-patch circ conv + LN + *v + proj -> out fp32

typedef unsigned short ushort;
typedef __attribute__((ext_vector_type(8))) short short8;
typedef __attribute__((ext_vector_type(4))) float floatx4;
typedef __attribute__((ext_vector_type(2))) unsigned int uint2v;
typedef __attribute__((ext_vector_type(4))) unsigned int uint4v;

#define CC 64
#define HID 384
#define HW 65536
#define QSU 68     // qb/kb row stride (ushorts, bf16): 136B, b64-aligned, ~2-way banks
#define TS 68      // t row stride (floats): 272B, 16B-aligned for ds_read_b128

#define WPT_OFF 0
#define XT_OFF  131072
#define XT_BYTES (4ull * HW * 64 * 2)
#define HID_OFF (XT_OFF + XT_BYTES)
#define HID_BYTES (384ull * HW * 2)
#define QKV_OFF (HID_OFF + HID_BYTES)

__device__ __forceinline__ float bu2f(ushort u) {
    union { float f; unsigned i; } v; v.i = ((unsigned)u) << 16; return v.f;
}
__device__ __forceinline__ ushort f2bu(float f) {
    __hip_bfloat16 h = __float2bfloat16(f);
    return *(ushort*)&h;
}
// packed dword of 2 bf16 -> 2 floats (1 VALU op per value)
__device__ __forceinline__ void unpk(unsigned d, float& lo, float& hi) {
    union { unsigned i; float f; } a, b;
    a.i = d << 16; b.i = d & 0xffff0000u;
    lo = a.f; hi = b.f;
}

__global__ __launch_bounds__(256) void kx_tr(
    const float* __restrict__ x, ushort* __restrict__ XT) {
    int b = blockIdx.y;
    int hw = blockIdx.x * 256 + threadIdx.x;
    const float* xb = x + ((size_t)b * CC) * HW;
    ushort* XTb = XT + ((size_t)b * HW + hw) * 64;
#pragma unroll 2
    for (int c0 = 0; c0 < 64; c0 += 8) {
        ushort v[8];
#pragma unroll
        for (int j = 0; j < 8; j++)
            v[j] = f2bu(xb[(size_t)(c0 + j) * HW + hw]);
        *(short8*)(XTb + c0) = *(short8*)v;
    }
}

// k0: wpT [c][o] = wp[o][c] fp32; WS mfma-swizzled w_hidden bf16
__global__ __launch_bounds__(256) void k0_prep(
    const float* __restrict__ wp, const float* __restrict__ wh,
    float* __restrict__ wpT, ushort* __restrict__ WS) {
    int t = threadIdx.x;
    for (int i = t; i < 8192; i += 256) {
        int c = i >> 6, o = i & 63;
        wpT[i] = wp[o * 128 + c];
    }
    for (int i = t; i < 24576; i += 256) {
        int j = i & 7;
        int lane = (i >> 3) & 63;
        int ks = (i >> 9) & 1;
        int mt = i >> 10;
        int o = mt * 16 + (lane & 15);
        int k = ks * 32 + ((lane >> 4) << 3) + j;
        WS[i] = f2bu(wh[o * 64 + k]);
    }
}

#define WS_OFF 32768

// k1: MFMA GEMM 64->384. Block 4 waves: 64 out x 256 pix.
__global__ __launch_bounds__(256) void k1_mfma(
    const ushort* __restrict__ XT, const ushort* __restrict__ WS,
    const float* __restrict__ bh, ushort* __restrict__ hid) {
    int tid = threadIdx.x;
    int lane = tid & 63, wave = tid >> 6;
    int lane15 = lane & 15, quad = lane >> 4;
    int pix0 = blockIdx.x * 256 + wave * 64;
    int o0 = blockIdx.y * 64;

    short8 a[4][2];
#pragma unroll
    for (int mt = 0; mt < 4; mt++) {
        int mtg = (o0 >> 4) + mt;
#pragma unroll
        for (int ks = 0; ks < 2; ks++)
            a[mt][ks] = *(const short8*)(WS + ((((mtg << 1) + ks) << 6) + lane) * 8);
    }
    floatx4 acc[4][4];
#pragma unroll
    for (int mt = 0; mt < 4; mt++)
#pragma unroll
        for (int nt = 0; nt < 4; nt++)
            acc[mt][nt] = (floatx4){0.f, 0.f, 0.f, 0.f};

#pragma unroll
    for (int nt = 0; nt < 4; nt++) {
        const ushort* bp0 = XT + ((size_t)(pix0 + nt * 16 + lane15) << 6) + quad * 8;
        short8 b0 = *(const short8*)(bp0);
        short8 b1 = *(const short8*)(bp0 + 32);
#pragma unroll
        for (int mt = 0; mt < 4; mt++) {
            acc[mt][nt] = __builtin_amdgcn_mfma_f32_16x16x32_bf16(a[mt][0], b0, acc[mt][nt], 0, 0, 0);
            acc[mt][nt] = __builtin_amdgcn_mfma_f32_16x16x32_bf16(a[mt][1], b1, acc[mt][nt], 0, 0, 0);
        }
    }
#pragma unroll
    for (int mt = 0; mt < 4; mt++) {
        int obase = o0 + mt * 16 + quad * 4;
        float b0 = bh[obase], b1 = bh[obase + 1], b2 = bh[obase + 2], b3 = bh[obase + 3];
#pragma unroll
        for (int nt = 0; nt < 4; nt++) {
            int pix = pix0 + nt * 16 + lane15;
            hid[(size_t)(obase + 0) * HW + pix] = f2bu(acc[mt][nt][0] + b0);
            hid[(size_t)(obase + 1) * HW + pix] = f2bu(acc[mt][nt][1] + b1);
            hid[(size_t)(obase + 2) * HW + pix] = f2bu(acc[mt][nt][2] + b2);
            hid[(size_t)(obase + 3) * HW + pix] = f2bu(acc[mt][nt][3] + b3);
        }
    }
}

// k2: dw 3x3 SAME + bias -> qkv PATCH-MAJOR [ch][patch][64].
// Block = 8 rows (one patch-row) x 1 ch. grid (32, 384).
__global__ __launch_bounds__(256) void k2_dw(
    const ushort* __restrict__ hid, const float* __restrict__ wdw,
    const float* __restrict__ bdw, ushort* __restrict__ qkv) {
    __shared__ float rows[10][258];
    __shared__ ushort stg[8 * 264];
    int tid = threadIdx.x;
    int ch = blockIdx.y;
    int pr = blockIdx.x;               // patch-row 0..31
    int r0 = pr * 8;
    const ushort* base = hid + (size_t)ch * HW;
    for (int rr = 0; rr < 10; rr++) {
        int r = r0 - 1 + rr;
        float v = 0.f;
        if (r >= 0 && r < 256) v = bu2f(base[(r << 8) + tid]);
        rows[rr][1 + tid] = v;
        if (tid == 0) { rows[rr][0] = 0.f; rows[rr][257] = 0.f; }
    }
    __syncthreads();
    float w00 = wdw[ch * 9 + 0], w01 = wdw[ch * 9 + 1], w02 = wdw[ch * 9 + 2];
    float w10 = wdw[ch * 9 + 3], w11 = wdw[ch * 9 + 4], w12 = wdw[ch * 9 + 5];
    float w20 = wdw[ch * 9 + 6], w21 = wdw[ch * 9 + 7], w22 = wdw[ch * 9 + 8];
    float bias = bdw[ch];
#pragma unroll
    for (int rr = 0; rr < 8; rr++) {
        float acc = bias
            + w00 * rows[rr][tid] + w01 * rows[rr][tid + 1] + w02 * rows[rr][tid + 2]
            + w10 * rows[rr + 1][tid] + w11 * rows[rr + 1][tid + 1] + w12 * rows[rr + 1][tid + 2]
            + w20 * rows[rr + 2][tid] + w21 * rows[rr + 2][tid + 1] + w22 * rows[rr + 2][tid + 2];
        stg[rr * 264 + tid] = f2bu(acc);
    }
    __syncthreads();
    // patch-major writeout: thread t -> 8 contiguous ushorts (fully coalesced 4KB)
    short8 v = *(const short8*)(stg + (tid & 7) * 264 + (tid >> 3) * 8);
    *(short8*)(qkv + (size_t)ch * HW + (size_t)pr * 2048 + tid * 8) = v;
}

// k3: per-patch circ conv + LN + *v + proj. qkv patch-major.
// Round-7: bf16 q/k staging + wp in LDS chunked 2x16KB. LDS 53,248B -> 3 blk/CU.
__global__ __launch_bounds__(256, 3) void k3_patch(
    const ushort* __restrict__ qkv, const float* __restrict__ wpTg,
    const float* __restrict__ bp, const float* __restrict__ lnw,
    const float* __restrict__ lnb, float* __restrict__ out, int b) {
    __shared__ float SH[13312];         // 53,248 B total
    ushort* qb_u = (ushort*)SH;         // bf16 [128][QSU] = 17,408 B
    ushort* kb_u = (ushort*)SH + 8704;  // bf16 [128][QSU] = 17,408 B
    float* tb = SH;                     // fp32 [128][TS] overlay (after B) = 34,816 B
    float* red = SH + 8704;             // 512 floats (after tb)
    float* wpc = SH + 9216;             // wp chunk [64][64] fp32 = 16,384 B (byte 36,864)

    int tid = threadIdx.x;
    int bid = blockIdx.x;
    // XCD-aware swizzle (grid=1024, 8 XCDs): xcd = bid%8 gets patches [xcd*128, +128)
    int p = ((bid & 7) << 7) | (bid >> 3);
    int prow = p >> 5, pcol = p & 31;

    // Phase A: coalesced patch-major loads -> bf16 LDS (stride QSU=68 ushorts)
    //          + wp chunk1 (cc 0..63) global -> LDS, consumed only at phase E
#pragma unroll
    for (int m = 0; m < 4; m++) {
        int f = m * 256 + tid;
        int c = f >> 3;
        int i8 = (f & 7) * 8;
        uint4v qv = *(const uint4v*)(qkv + (size_t)c * HW + (size_t)p * 64 + i8);
        uint4v kv = *(const uint4v*)(qkv + (size_t)(128 + c) * HW + (size_t)p * 64 + i8);
        uint2v* qd = (uint2v*)(qb_u + c * QSU + i8);
        uint2v* kd = (uint2v*)(kb_u + c * QSU + i8);
        qd[0] = (uint2v){qv.x, qv.y};
        qd[1] = (uint2v){qv.z, qv.w};
        kd[0] = (uint2v){kv.x, kv.y};
        kd[1] = (uint2v){kv.z, kv.w};
    }
#pragma unroll
    for (int j = 0; j < 4; j++)
        ((float4*)wpc)[j * 256 + tid] = ((const float4*)wpTg)[j * 256 + tid];
    __syncthreads();

    // Phase B: 2D circular conv. thread = (channel c, col-half h).
    int c = tid >> 1, h = tid & 1;
    float qr[64];
    {
        const ushort* qrow = qb_u + c * QSU;
#pragma unroll
        for (int j = 0; j < 16; j++) {
            uint2v d = *(const uint2v*)(qrow + 4 * j);
            unpk(d.x, qr[4 * j], qr[4 * j + 1]);
            unpk(d.y, qr[4 * j + 2], qr[4 * j + 3]);
        }
    }
    float acc[8][4];
#pragma unroll
    for (int r = 0; r < 8; r++)
#pragma unroll
        for (int sc = 0; sc < 4; sc++) acc[r][sc] = 0.f;
    {
        const ushort* krow = kb_u + c * QSU;
#pragma unroll 2
        for (int m = 0; m < 8; m++) {
            float kr[8];   // kr[v] = k[c][m][(v+4h)&7]
#pragma unroll
            for (int u2 = 0; u2 < 4; u2++) {
                int colo = (u2 * 2 + 4 * h) & 7;
                unsigned d = *(const unsigned*)(krow + m * 8 + colo);
                unpk(d, kr[u2 * 2], kr[u2 * 2 + 1]);
            }
#pragma unroll
            for (int r = 0; r < 8; r++) {
                int i = (r - m) & 7;
#pragma unroll
                for (int sc = 0; sc < 4; sc++)
#pragma unroll
                    for (int j = 0; j < 8; j++)
                        acc[r][sc] += qr[i * 8 + j] * kr[(sc - j) & 7];
            }
        }
    }
    __syncthreads();

    // Phase C: t -> LDS fp32 (stride TS=68), overlays q/k staging.
    // Also: wp chunk2 (cc 64..127) global -> named registers (hidden under LN + D).
#pragma unroll
    for (int r = 0; r < 8; r++) {
        float4 v = {acc[r][0], acc[r][1], acc[r][2], acc[r][3]};
        *(float4*)(tb + c * TS + r * 8 + h * 4) = v;
    }
    float4 wr0 = ((const float4*)wpTg)[1024 + 0 * 256 + tid];
    float4 wr1 = ((const float4*)wpTg)[1024 + 1 * 256 + tid];
    float4 wr2 = ((const float4*)wpTg)[1024 + 2 * 256 + tid];
    float4 wr3 = ((const float4*)wpTg)[1024 + 3 * 256 + tid];
    __syncthreads();

    // LN: per-pixel stats over 128 ch
    int pix = tid & 63, cg = tid >> 6;
    float sum = 0.f, sq = 0.f;
#pragma unroll
    for (int j = 0; j < 32; j++) {
        int cc = cg * 32 + j;
        float v = tb[cc * TS + pix];
        sum += v; sq += v * v;
    }
    red[cg * 64 + pix] = sum;
    red[256 + cg * 64 + pix] = sq;
    __syncthreads();
    float ts = red[pix] + red[64 + pix] + red[128 + pix] + red[192 + pix];
    float tq = red[256 + pix] + red[320 + pix] + red[384 + pix] + red[448 + pix];
    float mu = ts * (1.f / 128.f);
    float var = tq * (1.f / 128.f) - mu * mu;
    float rsig = rsqrtf(var + 1e-5f);

    // Phase D: t = ((t-mu)*rsig*lnw + lnb) * v   (in-place, per-pixel exclusive)
#pragma unroll 4
    for (int j = 0; j < 32; j++) {
        int cc = cg * 32 + j;
        float vv = bu2f(qkv[(size_t)(256 + cc) * HW + (size_t)p * 64 + pix]);
        float tv = tb[cc * TS + pix];
        tb[cc * TS + pix] = ((tv - mu) * rsig * lnw[cc] + lnb[cc]) * vv;
    }
    __syncthreads();

    // Phase E: proj 128->64 in two 64-cc passes over the 16KB wp chunk buffer.
    int oi = tid & 15, pg = tid >> 4;
    int o0 = oi * 4, pix0 = pg * 4;
    float pe[4][4];
#pragma unroll
    for (int oo = 0; oo < 4; oo++) {
        float bb = bp[o0 + oo];
#pragma unroll
        for (int pp = 0; pp < 4; pp++) pe[oo][pp] = bb;
    }
    // pass 1: cc 0..63 from chunk1 (already in LDS since phase A)
#pragma unroll 4
    for (int cc = 0; cc < 64; cc++) {
        float4 wv = *(const float4*)(wpc + cc * 64 + o0);
        float4 tv = *(const float4*)(tb + cc * TS + pix0);
        pe[0][0] += wv.x * tv.x; pe[0][1] += wv.x * tv.y; pe[0][2] += wv.x * tv.z; pe[0][3] += wv.x * tv.w;
        pe[1][0] += wv.y * tv.x; pe[1][1] += wv.y * tv.y; pe[1][2] += wv.y * tv.z; pe[1][3] += wv.y * tv.w;
        pe[2][0] += wv.z * tv.x; pe[2][1] += wv.z * tv.y; pe[2][2] += wv.z * tv.z; pe[2][3] += wv.z * tv.w;
        pe[3][0] += wv.w * tv.x; pe[3][1] += wv.w * tv.y; pe[3][2] += wv.w * tv.z; pe[3][3] += wv.w * tv.w;
    }
    __syncthreads();   // chunk1 fully consumed
    ((float4*)wpc)[0 * 256 + tid] = wr0;
    ((float4*)wpc)[1 * 256 + tid] = wr1;
    ((float4*)wpc)[2 * 256 + tid] = wr2;
    ((float4*)wpc)[3 * 256 + tid] = wr3;
    __syncthreads();   // chunk2 ready
    // pass 2: cc 64..127
#pragma unroll 4
    for (int cc = 0; cc < 64; cc++) {
        float4 wv = *(const float4*)(wpc + cc * 64 + o0);
        float4 tv = *(const float4*)(tb + (64 + cc) * TS + pix0);
        pe[0][0] += wv.x * tv.x; pe[0][1] += wv.x * tv.y; pe[0][2] += wv.x * tv.z; pe[0][3] += wv.x * tv.w;
        pe[1][0] += wv.y * tv.x; pe[1][1] += wv.y * tv.y; pe[1][2] += wv.y * tv.z; pe[1][3] += wv.y * tv.w;
        pe[2][0] += wv.z * tv.x; pe[2][1] += wv.z * tv.y; pe[2][2] += wv.z * tv.z; pe[2][3] += wv.z * tv.w;
        pe[3][0] += wv.w * tv.x; pe[3][1] += wv.w * tv.y; pe[3][2] += wv.w * tv.z; pe[3][3] += wv.w * tv.w;
    }
    int row = (prow << 3) + (pix0 >> 3);
    int col = (pcol << 3) + (pix0 & 7);
#pragma unroll
    for (int oo = 0; oo < 4; oo++) {
        float4 v = {pe[oo][0], pe[oo][1], pe[oo][2], pe[oo][3]};
        *(float4*)(out + (((size_t)(b * CC + o0 + oo)) << 16) + row * 256 + col) = v;
    }
}

extern "C" void kernel_launch(void* const* d_in, const int* in_sizes, int n_in,
                              void* d_out, int out_size, void* d_ws, size_t ws_size,
                              hipStream_t stream) {
    (void)in_sizes; (void)n_in; (void)out_size; (void)ws_size;
    const float* x   = (const float*)d_in[0];
    const float* wh  = (const float*)d_in[1];
    const float* bh  = (const float*)d_in[2];
    const float* wdw = (const float*)d_in[3];
    const float* bdw = (const float*)d_in[4];
    const float* wp  = (const float*)d_in[5];
    const float* bp  = (const float*)d_in[6];
    const float* lnw = (const float*)d_in[7];
    const float* lnb = (const float*)d_in[8];
    float* out = (float*)d_out;

    char* ws = (char*)d_ws;
    float* wpT = (float*)(ws + WPT_OFF);
    ushort* WS = (ushort*)(ws + WS_OFF);
    ushort* XT = (ushort*)(ws + XT_OFF);
    ushort* hid = (ushort*)(ws + HID_OFF);
    ushort* qkv = (ushort*)(ws + QKV_OFF);

    kx_tr<<<dim3(256, 4), dim3(256), 0, stream>>>(x, XT);
    k0_prep<<<dim3(1), dim3(256), 0, stream>>>(wp, wh, wpT, WS);

    for (int b = 0; b < 4; b++) {
        k1_mfma<<<dim3(256, 6), dim3(256), 0, stream>>>(
            XT + (size_t)b * HW * 64, WS, bh, hid);
        k2_dw<<<dim3(32, HID), dim3(256), 0, stream>>>(hid, wdw, bdw, qkv);
        k3_patch<<<dim3(1024), dim3(256), 0, stream>>>(qkv, wpT, bp, lnw, lnb, out, b);
    }
}

// Round 3
// 526.154 us; speedup vs baseline: 1.2783x; 1.2034x over previous
//
#include <hip/hip_runtime.h>
#include <hip/hip_bf16.h>

// FSAS_26766236188756 — round 8: FUSE k2 (dw 3x3) INTO k3. k1 writes hid
// PIXEL-MAJOR [px][384] bf16; fused k3 stages 10x10 halo chunks into LDS,
// computes dw in-kernel (bitwise-identical FMA order to old k2), q/k -> LDS
// bf16 (same layout phase B used), v computed at phase-D time into regs.
// qkv buffer eliminated (-100 MB/batch round trip + 4 dispatches).
// Freed space holds a 2nd hid buffer -> k1/k3 run with grid.z=2 (6 launches).

typedef unsigned short ushort;
typedef __attribute__((ext_vector_type(8))) short short8;
typedef __attribute__((ext_vector_type(4))) float floatx4;
typedef __attribute__((ext_vector_type(2))) unsigned int uint2v;
typedef __attribute__((ext_vector_type(4))) unsigned int uint4v;
typedef __attribute__((ext_vector_type(4))) unsigned short ushort4v;

#define CC 64
#define HID 384
#define HW 65536
#define QSU 68     // qb/kb row stride (ushorts, bf16)
#define TS 68      // t row stride (floats)
#define HS 68      // halo row stride (ushorts)

#define WPT_OFF 0
#define WS_OFF 32768
#define WDWT_OFF 81920
#define XT_OFF  131072
#define XT_BYTES (4ull * HW * 64 * 2)
#define HID_OFF (XT_OFF + XT_BYTES)
#define HID_BYTES (384ull * HW * 2)
#define HID_ELEMS ((size_t)HW * 384)

__device__ __forceinline__ float bu2f(ushort u) {
    union { float f; unsigned i; } v; v.i = ((unsigned)u) << 16; return v.f;
}
__device__ __forceinline__ ushort f2bu(float f) {
    __hip_bfloat16 h = __float2bfloat16(f);
    return *(ushort*)&h;
}
__device__ __forceinline__ float ubits(unsigned u) {
    union { unsigned i; float f; } v; v.i = u; return v.f;
}
// packed dword of 2 bf16 -> 2 floats
__device__ __forceinline__ void unpk(unsigned d, float& lo, float& hi) {
    lo = ubits(d << 16); hi = ubits(d & 0xffff0000u);
}

__global__ __launch_bounds__(256) void kx_tr(
    const float* __restrict__ x, ushort* __restrict__ XT) {
    int b = blockIdx.y;
    int hw = blockIdx.x * 256 + threadIdx.x;
    const float* xb = x + ((size_t)b * CC) * HW;
    ushort* XTb = XT + ((size_t)b * HW + hw) * 64;
#pragma unroll 2
    for (int c0 = 0; c0 < 64; c0 += 8) {
        ushort v[8];
#pragma unroll
        for (int j = 0; j < 8; j++)
            v[j] = f2bu(xb[(size_t)(c0 + j) * HW + hw]);
        *(short8*)(XTb + c0) = *(short8*)v;
    }
}

// k0: wpT [c][o]; WS mfma-swizzled w_hidden bf16; wdwT [9][384] transposed dw weights
__global__ __launch_bounds__(256) void k0_prep(
    const float* __restrict__ wp, const float* __restrict__ wh,
    const float* __restrict__ wdw,
    float* __restrict__ wpT, ushort* __restrict__ WS, float* __restrict__ wdwT) {
    int t = threadIdx.x;
    for (int i = t; i < 8192; i += 256) {
        int c = i >> 6, o = i & 63;
        wpT[i] = wp[o * 128 + c];
    }
    for (int i = t; i < 24576; i += 256) {
        int j = i & 7;
        int lane = (i >> 3) & 63;
        int ks = (i >> 9) & 1;
        int mt = i >> 10;
        int o = mt * 16 + (lane & 15);
        int k = ks * 32 + ((lane >> 4) << 3) + j;
        WS[i] = f2bu(wh[o * 64 + k]);
    }
    for (int i = t; i < 3456; i += 256) {
        int k = i / 384, ch = i - k * 384;
        wdwT[i] = wdw[ch * 9 + k];
    }
}

// k1: MFMA GEMM 64->384. Writes hid PIXEL-MAJOR [px][384] bf16. grid (256,6,2).
__global__ __launch_bounds__(256) void k1_mfma(
    const ushort* __restrict__ XT0, const ushort* __restrict__ WS,
    const float* __restrict__ bh, ushort* __restrict__ hid0) {
    int z = blockIdx.z;
    const ushort* XT = XT0 + (size_t)z * HW * 64;
    ushort* hid = hid0 + (size_t)z * HID_ELEMS;
    int tid = threadIdx.x;
    int lane = tid & 63, wave = tid >> 6;
    int lane15 = lane & 15, quad = lane >> 4;
    int pix0 = blockIdx.x * 256 + wave * 64;
    int o0 = blockIdx.y * 64;

    short8 a[4][2];
#pragma unroll
    for (int mt = 0; mt < 4; mt++) {
        int mtg = (o0 >> 4) + mt;
#pragma unroll
        for (int ks = 0; ks < 2; ks++)
            a[mt][ks] = *(const short8*)(WS + ((((mtg << 1) + ks) << 6) + lane) * 8);
    }
    floatx4 acc[4][4];
#pragma unroll
    for (int mt = 0; mt < 4; mt++)
#pragma unroll
        for (int nt = 0; nt < 4; nt++)
            acc[mt][nt] = (floatx4){0.f, 0.f, 0.f, 0.f};

#pragma unroll
    for (int nt = 0; nt < 4; nt++) {
        const ushort* bp0 = XT + ((size_t)(pix0 + nt * 16 + lane15) << 6) + quad * 8;
        short8 b0 = *(const short8*)(bp0);
        short8 b1 = *(const short8*)(bp0 + 32);
#pragma unroll
        for (int mt = 0; mt < 4; mt++) {
            acc[mt][nt] = __builtin_amdgcn_mfma_f32_16x16x32_bf16(a[mt][0], b0, acc[mt][nt], 0, 0, 0);
            acc[mt][nt] = __builtin_amdgcn_mfma_f32_16x16x32_bf16(a[mt][1], b1, acc[mt][nt], 0, 0, 0);
        }
    }
#pragma unroll
    for (int mt = 0; mt < 4; mt++) {
        int obase = o0 + mt * 16 + quad * 4;
        float b0 = bh[obase], b1 = bh[obase + 1], b2 = bh[obase + 2], b3 = bh[obase + 3];
#pragma unroll
        for (int nt = 0; nt < 4; nt++) {
            int pix = pix0 + nt * 16 + lane15;
            ushort4v h;
            h.x = f2bu(acc[mt][nt][0] + b0);
            h.y = f2bu(acc[mt][nt][1] + b1);
            h.z = f2bu(acc[mt][nt][2] + b2);
            h.w = f2bu(acc[mt][nt][3] + b3);
            *(ushort4v*)(hid + (size_t)pix * 384 + obase) = h;
        }
    }
}

// ---------- fused k3 helpers ----------
struct StReg { uint4v v[4]; };

__device__ __forceinline__ StReg stage_load(const ushort* __restrict__ hid,
                                            int r0, int c0, int cb, int tid) {
    StReg s;
#pragma unroll
    for (int it = 0; it < 4; it++) {
        int hp = it * 32 + (tid >> 3);
        int hr = hp / 10, hc = hp - hr * 10;
        int gr = r0 - 1 + hr, gc = c0 - 1 + hc;
        uint4v z = (uint4v){0u, 0u, 0u, 0u};
        if (hp < 100 && (unsigned)gr < 256u && (unsigned)gc < 256u)
            z = *(const uint4v*)(hid + (size_t)(gr * 256 + gc) * 384 + cb + (tid & 7) * 8);
        s.v[it] = z;
    }
    return s;
}

__device__ __forceinline__ void stage_write(ushort* halo_u, const StReg& s, int tid) {
#pragma unroll
    for (int it = 0; it < 4; it++) {
        int hp = it * 32 + (tid >> 3);
        if (hp < 100) {
            uint2v* d = (uint2v*)(halo_u + hp * HS + (tid & 7) * 8);
            d[0] = (uint2v){s.v[it].x, s.v[it].y};
            d[1] = (uint2v){s.v[it].z, s.v[it].w};
        }
    }
}

// dw 3x3 for 64 q-or-k channels. thread = (ch-pair c2, out-row po).
// FMA order identical to old k2: bias, then (dr,dc) ascending.
__device__ __forceinline__ void dw_qk(const ushort* halo_u, ushort* dst,
        const float* __restrict__ wdwT, const float* __restrict__ bdw,
        int gcb, int rowbase, int tid) {
    int c2 = tid & 31, po = tid >> 5;
    int gch = gcb + c2 * 2;
    float w0[9], w1[9];
#pragma unroll
    for (int k = 0; k < 9; k++) {
        w0[k] = wdwT[k * 384 + gch];
        w1[k] = wdwT[k * 384 + gch + 1];
    }
    float b0 = bdw[gch], b1 = bdw[gch + 1];
    float a0[8], a1[8];
#pragma unroll
    for (int c = 0; c < 8; c++) { a0[c] = b0; a1[c] = b1; }
#pragma unroll
    for (int dr = 0; dr < 3; dr++) {
        int hb = (po + dr) * 10;
        float hx[10], hy[10];
#pragma unroll
        for (int i = 0; i < 10; i++) {
            unsigned d = *(const unsigned*)(halo_u + (hb + i) * HS + c2 * 2);
            unpk(d, hx[i], hy[i]);
        }
#pragma unroll
        for (int c = 0; c < 8; c++)
#pragma unroll
            for (int dc = 0; dc < 3; dc++) {
                a0[c] += w0[dr * 3 + dc] * hx[c + dc];
                a1[c] += w1[dr * 3 + dc] * hy[c + dc];
            }
    }
    ushort* r0p = dst + (rowbase + c2 * 2) * QSU + po * 8;
    ushort* r1p = r0p + QSU;
#pragma unroll
    for (int c = 0; c < 8; c += 2) {
        *(unsigned*)(r0p + c) = (unsigned)f2bu(a0[c]) | ((unsigned)f2bu(a0[c + 1]) << 16);
        *(unsigned*)(r1p + c) = (unsigned)f2bu(a1[c]) | ((unsigned)f2bu(a1[c + 1]) << 16);
    }
}

// dw 3x3 for 64 v channels + immediate LN-apply into tb.
// thread = (pix, cj wave). weights/bias/ln via scalar loads (wave-uniform ch).
__device__ __forceinline__ void dw_v_apply(const ushort* halo_u, float* tb,
        const float* __restrict__ wdwT, const float* __restrict__ bdw,
        const float* __restrict__ lnw, const float* __restrict__ lnb,
        int gcb, int ccb, int pix, int cj, float mu, float rsig) {
    int r = pix >> 3, cs = pix & 7;
    int ch0 = __builtin_amdgcn_readfirstlane(gcb + cj * 16);
    int ccs = ch0 - 256;   // scalar cc base
    float acc[16];
#pragma unroll
    for (int jj = 0; jj < 16; jj++) acc[jj] = bdw[ch0 + jj];
#pragma unroll
    for (int dr = 0; dr < 3; dr++) {
#pragma unroll
        for (int dc = 0; dc < 3; dc++) {
            int npx = (r + dr) * 10 + cs + dc;
            const ushort* hp = halo_u + npx * HS + (cj * 16);
            uint2v d0 = *(const uint2v*)(hp);
            uint2v d1 = *(const uint2v*)(hp + 4);
            uint2v d2 = *(const uint2v*)(hp + 8);
            uint2v d3 = *(const uint2v*)(hp + 12);
            unsigned dd[8] = {d0.x, d0.y, d1.x, d1.y, d2.x, d2.y, d3.x, d3.y};
#pragma unroll
            for (int jj = 0; jj < 16; jj++) {
                unsigned u = dd[jj >> 1];
                float hv = (jj & 1) ? ubits(u & 0xffff0000u) : ubits(u << 16);
                acc[jj] += wdwT[(dr * 3 + dc) * 384 + ch0 + jj] * hv;
            }
        }
    }
#pragma unroll
    for (int jj = 0; jj < 16; jj++) {
        int cc = ccs + cj * 0 + (ccb - ccb) + (ccs - ccs) + (ccb + (ch0 - 256 - ccb)) + jj; // = ccs+jj
        cc = ccs + jj;
        float vv = bu2f(f2bu(acc[jj]));   // v passes through bf16 (matches old pipeline)
        float tv = tb[cc * TS + pix];
        tb[cc * TS + pix] = ((tv - mu) * rsig * lnw[ccs + jj] + lnb[ccs + jj]) * vv;
    }
}

// k3f: fused dw + circ conv + LN + *v + proj. grid (1024, 2).
__global__ __launch_bounds__(256, 3) void k3_fused(
    const ushort* __restrict__ hid0, const float* __restrict__ wpTg,
    const float* __restrict__ bp, const float* __restrict__ lnw,
    const float* __restrict__ lnb, const float* __restrict__ wdwT,
    const float* __restrict__ bdw, float* __restrict__ out, int bb) {
    __shared__ float SH[13312];            // 53,248 B
    ushort* qb_u = (ushort*)SH;            // bf16 [128][68]  bytes 0..17407
    ushort* kb_u = (ushort*)SH + 8704;     // bf16 [128][68]  bytes 17408..34815
    float* tb = SH;                        // f32 [128][68] overlay (after B)
    float* red = SH + 8704;                // 512 f           bytes 34816..36863
    ushort* halo_u = (ushort*)SH + 18432;  // [100][68]u      bytes 36864..50463
    float* wpc = SH + 9216;                // [64][64] f32 overlay of halo, bytes 36864..53247

    int tid = threadIdx.x;
    int z = blockIdx.y;
    const ushort* hid = hid0 + (size_t)z * HID_ELEMS;
    int b = bb * 2 + z;
    int bid = blockIdx.x;
    int p = ((bid & 7) << 7) | (bid >> 3);   // XCD swizzle
    int prow = p >> 5, pcol = p & 31;
    int r0 = prow * 8, c0 = pcol * 8;

    // ---- dw chunks 0..3 (q: hid ch 0..127 / k: 128..255), prefetch-chained ----
    StReg s = stage_load(hid, r0, c0, 0, tid);
#pragma unroll
    for (int ci = 0; ci < 4; ci++) {
        if (ci) __syncthreads();             // prior chunk's halo reads done
        stage_write(halo_u, s, tid);
        __syncthreads();                     // halo ready
        s = stage_load(hid, r0, c0, (ci + 1) * 64, tid);   // prefetch next (ci=3 -> v chunk)
        dw_qk(halo_u, (ci < 2 ? qb_u : kb_u), wdwT, bdw, ci * 64, (ci & 1) * 64, tid);
    }
    __syncthreads();                         // chunk3 halo reads done
    stage_write(halo_u, s, tid);             // chunk4 (v ch 256..319)
    __syncthreads();                         // halo4 ready; qb/kb complete

    // ---- Phase B: 2D circular conv. thread = (channel c, col-half h). ----
    int c = tid >> 1, h = tid & 1;
    float qr[64];
    {
        const ushort* qrow = qb_u + c * QSU;
#pragma unroll
        for (int j = 0; j < 16; j++) {
            uint2v d = *(const uint2v*)(qrow + 4 * j);
            unpk(d.x, qr[4 * j], qr[4 * j + 1]);
            unpk(d.y, qr[4 * j + 2], qr[4 * j + 3]);
        }
    }
    float acc[8][4];
#pragma unroll
    for (int r = 0; r < 8; r++)
#pragma unroll
        for (int sc = 0; sc < 4; sc++) acc[r][sc] = 0.f;
    {
        const ushort* krow = kb_u + c * QSU;
#pragma unroll 2
        for (int m = 0; m < 8; m++) {
            float kr[8];
#pragma unroll
            for (int u2 = 0; u2 < 4; u2++) {
                int colo = (u2 * 2 + 4 * h) & 7;
                unsigned d = *(const unsigned*)(krow + m * 8 + colo);
                unpk(d, kr[u2 * 2], kr[u2 * 2 + 1]);
            }
#pragma unroll
            for (int r = 0; r < 8; r++) {
                int i = (r - m) & 7;
#pragma unroll
                for (int sc = 0; sc < 4; sc++)
#pragma unroll
                    for (int j = 0; j < 8; j++)
                        acc[r][sc] += qr[i * 8 + j] * kr[(sc - j) & 7];
            }
        }
    }
    __syncthreads();                          // B reads done -> tb overlay safe

    // ---- Phase C: t -> tb; issue chunk5 + wp-chunk1 loads ----
#pragma unroll
    for (int r = 0; r < 8; r++) {
        float4 v = {acc[r][0], acc[r][1], acc[r][2], acc[r][3]};
        *(float4*)(tb + c * TS + r * 8 + h * 4) = v;
    }
    StReg s5 = stage_load(hid, r0, c0, 320, tid);   // v ch 320..383
    float4 wa0 = ((const float4*)wpTg)[0 * 256 + tid];
    float4 wa1 = ((const float4*)wpTg)[1 * 256 + tid];
    float4 wa2 = ((const float4*)wpTg)[2 * 256 + tid];
    float4 wa3 = ((const float4*)wpTg)[3 * 256 + tid];
    __syncthreads();                          // tb ready

    // ---- LN stats ----
    int pix = tid & 63, cg = tid >> 6;
    float sum = 0.f, sq = 0.f;
#pragma unroll
    for (int j = 0; j < 32; j++) {
        int cc = cg * 32 + j;
        float v = tb[cc * TS + pix];
        sum += v; sq += v * v;
    }
    red[cg * 64 + pix] = sum;
    red[256 + cg * 64 + pix] = sq;
    __syncthreads();
    float ts = red[pix] + red[64 + pix] + red[128 + pix] + red[192 + pix];
    float tq = red[256 + pix] + red[320 + pix] + red[384 + pix] + red[448 + pix];
    float mu = ts * (1.f / 128.f);
    float var = tq * (1.f / 128.f) - mu * mu;
    float rsig = rsqrtf(var + 1e-5f);

    // ---- dw v chunk4 + LN-apply (cc 0..63) ----
    dw_v_apply(halo_u, tb, wdwT, bdw, lnw, lnb, 256, 0, pix, cg, mu, rsig);
    __syncthreads();                          // halo4 reads done
    stage_write(halo_u, s5, tid);
    __syncthreads();                          // halo5 ready
    dw_v_apply(halo_u, tb, wdwT, bdw, lnw, lnb, 320, 64, pix, cg, mu, rsig);
    __syncthreads();                          // halo5 reads done -> wpc region free

    // ---- wp chunk1 -> LDS ----
    ((float4*)wpc)[0 * 256 + tid] = wa0;
    ((float4*)wpc)[1 * 256 + tid] = wa1;
    ((float4*)wpc)[2 * 256 + tid] = wa2;
    ((float4*)wpc)[3 * 256 + tid] = wa3;
    __syncthreads();                          // wpc1 ready; all tb applied

    // ---- Phase E: proj 128->64, two 64-cc passes ----
    int oi = tid & 15, pg = tid >> 4;
    int o0 = oi * 4, pix0 = pg * 4;
    float pe[4][4];
#pragma unroll
    for (int oo = 0; oo < 4; oo++) {
        float bbv = bp[o0 + oo];
#pragma unroll
        for (int pp = 0; pp < 4; pp++) pe[oo][pp] = bbv;
    }
    // issue wp chunk2 loads early (hidden under pass 1)
    float4 wb0 = ((const float4*)wpTg)[1024 + 0 * 256 + tid];
    float4 wb1 = ((const float4*)wpTg)[1024 + 1 * 256 + tid];
    float4 wb2 = ((const float4*)wpTg)[1024 + 2 * 256 + tid];
    float4 wb3 = ((const float4*)wpTg)[1024 + 3 * 256 + tid];
#pragma unroll 4
    for (int cc = 0; cc < 64; cc++) {
        float4 wv = *(const float4*)(wpc + cc * 64 + o0);
        float4 tv = *(const float4*)(tb + cc * TS + pix0);
        pe[0][0] += wv.x * tv.x; pe[0][1] += wv.x * tv.y; pe[0][2] += wv.x * tv.z; pe[0][3] += wv.x * tv.w;
        pe[1][0] += wv.y * tv.x; pe[1][1] += wv.y * tv.y; pe[1][2] += wv.y * tv.z; pe[1][3] += wv.y * tv.w;
        pe[2][0] += wv.z * tv.x; pe[2][1] += wv.z * tv.y; pe[2][2] += wv.z * tv.z; pe[2][3] += wv.z * tv.w;
        pe[3][0] += wv.w * tv.x; pe[3][1] += wv.w * tv.y; pe[3][2] += wv.w * tv.z; pe[3][3] += wv.w * tv.w;
    }
    __syncthreads();
    ((float4*)wpc)[0 * 256 + tid] = wb0;
    ((float4*)wpc)[1 * 256 + tid] = wb1;
    ((float4*)wpc)[2 * 256 + tid] = wb2;
    ((float4*)wpc)[3 * 256 + tid] = wb3;
    __syncthreads();
#pragma unroll 4
    for (int cc = 0; cc < 64; cc++) {
        float4 wv = *(const float4*)(wpc + cc * 64 + o0);
        float4 tv = *(const float4*)(tb + (64 + cc) * TS + pix0);
        pe[0][0] += wv.x * tv.x; pe[0][1] += wv.x * tv.y; pe[0][2] += wv.x * tv.z; pe[0][3] += wv.x * tv.w;
        pe[1][0] += wv.y * tv.x; pe[1][1] += wv.y * tv.y; pe[1][2] += wv.y * tv.z; pe[1][3] += wv.y * tv.w;
        pe[2][0] += wv.z * tv.x; pe[2][1] += wv.z * tv.y; pe[2][2] += wv.z * tv.z; pe[2][3] += wv.z * tv.w;
        pe[3][0] += wv.w * tv.x; pe[3][1] += wv.w * tv.y; pe[3][2] += wv.w * tv.z; pe[3][3] += wv.w * tv.w;
    }
    int row = (prow << 3) + (pix0 >> 3);
    int col = (pcol << 3) + (pix0 & 7);
#pragma unroll
    for (int oo = 0; oo < 4; oo++) {
        float4 v = {pe[oo][0], pe[oo][1], pe[oo][2], pe[oo][3]};
        *(float4*)(out + (((size_t)(b * CC + o0 + oo)) << 16) + row * 256 + col) = v;
    }
}

extern "C" void kernel_launch(void* const* d_in, const int* in_sizes, int n_in,
                              void* d_out, int out_size, void* d_ws, size_t ws_size,
                              hipStream_t stream) {
    (void)in_sizes; (void)n_in; (void)out_size; (void)ws_size;
    const float* x   = (const float*)d_in[0];
    const float* wh  = (const float*)d_in[1];
    const float* bh  = (const float*)d_in[2];
    const float* wdw = (const float*)d_in[3];
    const float* bdw = (const float*)d_in[4];
    const float* wp  = (const float*)d_in[5];
    const float* bp  = (const float*)d_in[6];
    const float* lnw = (const float*)d_in[7];
    const float* lnb = (const float*)d_in[8];
    float* out = (float*)d_out;

    char* ws = (char*)d_ws;
    float* wpT = (float*)(ws + WPT_OFF);
    ushort* WS = (ushort*)(ws + WS_OFF);
    float* wdwT = (float*)(ws + WDWT_OFF);
    ushort* XT = (ushort*)(ws + XT_OFF);
    ushort* hid = (ushort*)(ws + HID_OFF);   // 2 batch buffers back-to-back

    kx_tr<<<dim3(256, 4), dim3(256), 0, stream>>>(x, XT);
    k0_prep<<<dim3(1), dim3(256), 0, stream>>>(wp, wh, wdw, wpT, WS, wdwT);

    for (int bb = 0; bb < 2; bb++) {
        k1_mfma<<<dim3(256, 6, 2), dim3(256), 0, stream>>>(
            XT + (size_t)bb * 2 * HW * 64, WS, bh, hid);
        k3_fused<<<dim3(1024, 2), dim3(256), 0, stream>>>(
            hid, wpT, bp, lnw, lnb, wdwT, bdw, out, bb);
    }
}